// Round 2
// baseline (2880.033 us; speedup 1.0000x reference)
//
#include <hip/hip_runtime.h>
#include <math.h>

// Problem constants
constexpr int DIM    = 2048;
constexpr int NEXP   = 64;
constexpr int TOPK   = 8;
constexpr int T_TOT  = 32768;        // 4 * 8192 tokens

// Tiling
constexpr int TTILE  = 64;           // tokens per block
constexpr int BK     = 64;           // k-chunk (256 B per row per step)
constexpr int NSTEP  = DIM / BK;     // 32

// Ambiguity guard: f32-vs-exact score deviation is ~1e-6 rms (hard bound <6e-5).
// Any token whose sorted top-9 has an adjacent gap below this is re-resolved in f64.
constexpr float GAP_TH = 5.0e-4f;

// Output layout (float32, reference return order)
constexpr size_t OFF_W   = 0;                      // top_w   [T,8]
constexpr size_t OFF_IDX = (size_t)T_TOT * TOPK;   // top_idx [T,8] (as float)
constexpr size_t OFF_B   = OFF_IDX * 2;            // new_adaptive_bias [64]
constexpr size_t OFF_U   = OFF_B + NEXP;           // new_expert_usage  [64]

// ws (uint32) layout: [0..63] expert counts | [64] n_flagged | [65..] flagged token ids
// requires ws_size >= (65 + T_TOT) * 4 = 131,332 bytes

#define MAC(i, j, A, B) \
    acc[i][j] = fmaf(A.x, B.x, acc[i][j]); \
    acc[i][j] = fmaf(A.y, B.y, acc[i][j]); \
    acc[i][j] = fmaf(A.z, B.z, acc[i][j]); \
    acc[i][j] = fmaf(A.w, B.w, acc[i][j]);

__global__ __launch_bounds__(256, 2)
void moe_gate_main(const float* __restrict__ x,
                   const float* __restrict__ gw,
                   const float* __restrict__ bias,
                   float* __restrict__ out,
                   unsigned int* __restrict__ ws)
{
    // 4 tiles of 16 KB: W0 | X0 | W1 | X1  (double-buffered). Reused for scores after.
    __shared__ __align__(16) char smem[65536];
    __shared__ unsigned int hist[NEXP];

    const int tid = threadIdx.x;
    const int t0  = blockIdx.x * TTILE;

    if (tid < NEXP) hist[tid] = 0;

    // ---- reg-staging geometry: 4 float4 per array per thread ----
    // f = tid + 256*s -> row = f>>4 (0..63), chunk c = f&15.
    // Global read is lane-LINEAR (16 consecutive lanes read one contiguous 256B
    // row slice) -> perfect coalescing through the normal cached path.
    // LDS write applies the XOR swizzle: chunk c of row r lands at slot c^(r&7).
    const float* xg[4];
    const float* wg[4];
    int wsl[4];
    #pragma unroll
    for (int s = 0; s < 4; ++s) {
        const int f = tid + 256 * s;
        const int r = f >> 4;
        const int c = f & 15;
        xg[s]  = x  + (size_t)(t0 + r) * DIM + 4 * c;
        wg[s]  = gw + (size_t)r        * DIM + 4 * c;
        wsl[s] = r * 256 + ((c ^ (r & 7)) << 4);          // byte offset in 16KB tile
    }

    char* const W0 = smem;
    char* const X0 = smem + 16384;
    char* const W1 = smem + 32768;
    char* const X1 = smem + 49152;

    float acc[4][4];
    #pragma unroll
    for (int i = 0; i < 4; ++i)
        #pragma unroll
        for (int j = 0; j < 4; ++j) acc[i][j] = 0.0f;

    float4 xr[4], wr[4];

    // prologue: stage tile 0 into buffer 0
    #pragma unroll
    for (int s = 0; s < 4; ++s) { xr[s] = *(const float4*)xg[s]; wr[s] = *(const float4*)wg[s]; }
    #pragma unroll
    for (int s = 0; s < 4; ++s) {
        *(float4*)(X0 + wsl[s]) = xr[s];
        *(float4*)(W0 + wsl[s]) = wr[s];
    }

    // compute-side mapping: experts eg+16i, tokens tg+16j (stride-16 rows ->
    // 16 lanes hit 16 distinct (r&7) classes -> <=2-way LDS aliasing, free)
    const int eg = tid & 15;
    const int tg = tid >> 4;
    const int wx = (eg & 7) << 4;
    const int tx = (tg & 7) << 4;

    #pragma unroll 1
    for (int step = 0; step < NSTEP; ++step) {
        const int cur = step & 1;
        const char* Wl = cur ? W1 : W0;
        const char* Xl = cur ? X1 : X0;
        __syncthreads();             // buf[cur] (written at end of prev step) visible
        // issue next tile's global loads AFTER the barrier: they fly under the
        // 1024-FMA compute phase and drain at the trailing ds_write (no barrier drain)
        if (step + 1 < NSTEP) {
            const int ko = (step + 1) * BK;
            #pragma unroll
            for (int s = 0; s < 4; ++s) {
                xr[s] = *(const float4*)(xg[s] + ko);
                wr[s] = *(const float4*)(wg[s] + ko);
            }
        }
        const char* wb = Wl + eg * 256;
        const char* xb = Xl + tg * 256;
        #pragma unroll
        for (int q = 0; q < 16; ++q) {
            const int wq = (q << 4) ^ wx;                // swizzled read slot
            const int xq = (q << 4) ^ tx;
            const float4 a0 = *(const float4*)(wb + wq);
            const float4 a1 = *(const float4*)(wb + 4096  + wq);
            const float4 a2 = *(const float4*)(wb + 8192  + wq);
            const float4 a3 = *(const float4*)(wb + 12288 + wq);
            const float4 b0 = *(const float4*)(xb + xq);
            const float4 b1 = *(const float4*)(xb + 4096  + xq);
            const float4 b2 = *(const float4*)(xb + 8192  + xq);
            const float4 b3 = *(const float4*)(xb + 12288 + xq);
            MAC(0,0,a0,b0) MAC(0,1,a0,b1) MAC(0,2,a0,b2) MAC(0,3,a0,b3)
            MAC(1,0,a1,b0) MAC(1,1,a1,b1) MAC(1,2,a1,b2) MAC(1,3,a1,b3)
            MAC(2,0,a2,b0) MAC(2,1,a2,b1) MAC(2,2,a2,b2) MAC(2,3,a2,b3)
            MAC(3,0,a3,b0) MAC(3,1,a3,b1) MAC(3,2,a3,b2) MAC(3,3,a3,b3)
        }
        if (step + 1 < NSTEP) {
            char* Wn = cur ? W0 : W1;                    // write the OTHER buffer
            char* Xn = cur ? X0 : X1;
            #pragma unroll
            for (int s = 0; s < 4; ++s) {
                *(float4*)(Xn + wsl[s]) = xr[s];
                *(float4*)(Wn + wsl[s]) = wr[s];
            }
        }
    }

    // ---- dump scores (+bias) to LDS: S[e][t], stride 65 floats ----
    // (S occupies bytes 0..16640 = W0/X0 region; last compute step reads W1/X1)
    __syncthreads();
    float* S = (float*)smem;
    #pragma unroll
    for (int i = 0; i < 4; ++i) {
        const int e = eg + 16 * i;
        const float b = bias[e];
        #pragma unroll
        for (int j = 0; j < 4; ++j)
            S[e * 65 + tg + 16 * j] = acc[i][j] + b;
    }
    __syncthreads();

    if (tid < TTILE) {
        const int t = tid;
        // top-9 (descending, lowest index first on ties — strict '>')
        float bv[9]; int bi[9];
        #pragma unroll
        for (int j = 0; j < 9; ++j) { bv[j] = -INFINITY; bi[j] = 0; }
        for (int e = 0; e < NEXP; ++e) {
            const float v = S[e * 65 + t];
            if (v > bv[8]) {
                bv[8] = v; bi[8] = e;
                #pragma unroll
                for (int j = 8; j > 0; --j) {
                    if (bv[j] > bv[j - 1]) {
                        const float tv = bv[j]; bv[j] = bv[j-1]; bv[j-1] = tv;
                        const int   ti = bi[j]; bi[j] = bi[j-1]; bi[j-1] = ti;
                    }
                }
            }
        }
        // ambiguity: any adjacent gap in sorted top-9 below guard -> f64 refine
        float ming = bv[0] - bv[1];
        #pragma unroll
        for (int j = 1; j < 8; ++j) ming = fminf(ming, bv[j] - bv[j + 1]);
        const bool amb = (ming < GAP_TH);

        const float m = bv[0];
        float Z = 0.0f;
        for (int e = 0; e < NEXP; ++e) Z += expf(S[e * 65 + t] - m);
        const float rZ = 1.0f / Z;
        float p[TOPK]; float wsum = 0.0f;
        #pragma unroll
        for (int j = 0; j < TOPK; ++j) { p[j] = expf(bv[j] - m) * rZ; wsum += p[j]; }
        const float rd = 1.0f / (wsum + 1e-8f);

        const size_t tglob = (size_t)(t0 + t);
        float4 w0 = { p[0]*rd, p[1]*rd, p[2]*rd, p[3]*rd };
        float4 w1 = { p[4]*rd, p[5]*rd, p[6]*rd, p[7]*rd };
        *(float4*)(out + OFF_W + tglob * TOPK)     = w0;
        *(float4*)(out + OFF_W + tglob * TOPK + 4) = w1;
        float4 i0 = { (float)bi[0], (float)bi[1], (float)bi[2], (float)bi[3] };
        float4 i1 = { (float)bi[4], (float)bi[5], (float)bi[6], (float)bi[7] };
        *(float4*)(out + OFF_IDX + tglob * TOPK)     = i0;
        *(float4*)(out + OFF_IDX + tglob * TOPK + 4) = i1;

        if (!amb) {
            #pragma unroll
            for (int j = 0; j < TOPK; ++j) atomicAdd(&hist[bi[j]], 1u);
        } else {
            const unsigned slot = atomicAdd(ws + NEXP, 1u);   // flag for refine
            ws[NEXP + 1 + slot] = (unsigned)tglob;
        }
    }

    __syncthreads();
    if (tid < NEXP) atomicAdd(ws + tid, hist[tid]);
}

// f64 re-resolve of flagged tokens: identical math/rounding/tie semantics as the
// previously-passing f64 kernel ((float)acc + bias, strict-> insertion, expf softmax).
__global__ __launch_bounds__(256)
void moe_gate_refine(const float* __restrict__ x,
                     const float* __restrict__ gw,
                     const float* __restrict__ bias,
                     float* __restrict__ out,
                     unsigned int* __restrict__ ws)
{
    __shared__ __align__(16) float xs[DIM];
    __shared__ float S[NEXP];
    const unsigned nflag = ws[NEXP];
    const unsigned* list = ws + NEXP + 1;

    for (unsigned ii = blockIdx.x; ii < nflag; ii += gridDim.x) {
        const size_t t = (size_t)list[ii];
        __syncthreads();                         // protect xs/S reuse across iters
        #pragma unroll
        for (int jj = 0; jj < 2; ++jj) {
            const int f = threadIdx.x + jj * 256;     // float4 index 0..511
            ((float4*)xs)[f] = ((const float4*)(x + t * DIM))[f];
        }
        __syncthreads();

        const int e = threadIdx.x >> 2;          // 4 threads per expert
        const int q = threadIdx.x & 3;
        const float* wr = gw + (size_t)e * DIM + q * 512;
        const float* xr = xs + q * 512;
        double s = 0.0;
        for (int k = 0; k < 512; k += 4) {
            const float4 wv4 = *(const float4*)(wr + k);
            const float4 xv4 = *(const float4*)(xr + k);
            s = fma((double)wv4.x, (double)xv4.x, s);
            s = fma((double)wv4.y, (double)xv4.y, s);
            s = fma((double)wv4.z, (double)xv4.z, s);
            s = fma((double)wv4.w, (double)xv4.w, s);
        }
        s += __shfl_down(s, 2, 4);
        s += __shfl_down(s, 1, 4);
        if (q == 0) S[e] = (float)s + bias[e];
        __syncthreads();

        if (threadIdx.x == 0) {
            float bv[TOPK]; int bi[TOPK];
            #pragma unroll
            for (int j = 0; j < TOPK; ++j) { bv[j] = -INFINITY; bi[j] = 0; }
            for (int e2 = 0; e2 < NEXP; ++e2) {
                const float v = S[e2];
                if (v > bv[TOPK - 1]) {
                    bv[TOPK - 1] = v; bi[TOPK - 1] = e2;
                    #pragma unroll
                    for (int j = TOPK - 1; j > 0; --j) {
                        if (bv[j] > bv[j - 1]) {
                            const float tv = bv[j]; bv[j] = bv[j-1]; bv[j-1] = tv;
                            const int   ti = bi[j]; bi[j] = bi[j-1]; bi[j-1] = ti;
                        }
                    }
                }
            }
            const float m = bv[0];
            float Z = 0.0f;
            for (int e2 = 0; e2 < NEXP; ++e2) Z += expf(S[e2] - m);
            const float rZ = 1.0f / Z;
            float p[TOPK]; float wsum = 0.0f;
            #pragma unroll
            for (int j = 0; j < TOPK; ++j) { p[j] = expf(bv[j] - m) * rZ; wsum += p[j]; }
            const float rd = 1.0f / (wsum + 1e-8f);

            float4 w0 = { p[0]*rd, p[1]*rd, p[2]*rd, p[3]*rd };
            float4 w1 = { p[4]*rd, p[5]*rd, p[6]*rd, p[7]*rd };
            *(float4*)(out + OFF_W + t * TOPK)     = w0;
            *(float4*)(out + OFF_W + t * TOPK + 4) = w1;
            float4 i0 = { (float)bi[0], (float)bi[1], (float)bi[2], (float)bi[3] };
            float4 i1 = { (float)bi[4], (float)bi[5], (float)bi[6], (float)bi[7] };
            *(float4*)(out + OFF_IDX + t * TOPK)     = i0;
            *(float4*)(out + OFF_IDX + t * TOPK + 4) = i1;

            #pragma unroll
            for (int j = 0; j < TOPK; ++j) atomicAdd(ws + bi[j], 1u);
        }
    }
}

__global__ void moe_gate_fin(const unsigned int* __restrict__ cnt,
                             const float* __restrict__ bias,
                             const float* __restrict__ eu,
                             float* __restrict__ out)
{
    const int e = threadIdx.x;
    const float usage = (float)cnt[e] * (1.0f / (float)(T_TOT * TOPK));
    out[OFF_B + e] = bias[e] - 0.01f * (usage - 1.0f / (float)NEXP);
    out[OFF_U + e] = 0.9f * eu[e] + 0.1f * usage;
}

extern "C" void kernel_launch(void* const* d_in, const int* in_sizes, int n_in,
                              void* d_out, int out_size, void* d_ws, size_t ws_size,
                              hipStream_t stream) {
    const float* x    = (const float*)d_in[0];
    const float* gw   = (const float*)d_in[1];
    const float* bias = (const float*)d_in[2];
    const float* eu   = (const float*)d_in[3];
    float* out = (float*)d_out;
    unsigned int* cnt = (unsigned int*)d_ws;

    hipMemsetAsync(cnt, 0, (NEXP + 1) * sizeof(unsigned int), stream);
    moe_gate_main<<<T_TOT / TTILE, 256, 0, stream>>>(x, gw, bias, out, cnt);
    moe_gate_refine<<<256, 256, 0, stream>>>(x, gw, bias, out, cnt);
    moe_gate_fin<<<1, NEXP, 0, stream>>>(cnt, bias, eu, out);
}

// Round 5
// 577.984 us; speedup vs baseline: 4.9829x; 4.9829x over previous
//
#include <hip/hip_runtime.h>
#include <math.h>

// Problem constants
constexpr int DIM    = 2048;
constexpr int NEXP   = 64;
constexpr int TOPK   = 8;
constexpr int T_TOT  = 32768;        // 4 * 8192 tokens

// Tiling
constexpr int TTILE  = 64;           // tokens per block
constexpr int BK     = 64;           // k-chunk (256 B per row per step)
constexpr int NSTEP  = DIM / BK;     // 32

// Ambiguity guard: f32-vs-exact score deviation is ~1e-6 rms (hard bound <6e-5).
// Any token whose sorted top-9 has an adjacent gap below this is re-resolved in f64.
constexpr float GAP_TH = 5.0e-4f;

// Output layout (float32, reference return order)
constexpr size_t OFF_W   = 0;                      // top_w   [T,8]
constexpr size_t OFF_IDX = (size_t)T_TOT * TOPK;   // top_idx [T,8] (as float)
constexpr size_t OFF_B   = OFF_IDX * 2;            // new_adaptive_bias [64]
constexpr size_t OFF_U   = OFF_B + NEXP;           // new_expert_usage  [64]

// ws (uint32) layout: [0..63] expert counts | [64] n_flagged | [65..] flagged ids
// Capacity of the flagged list is computed HOST-SIDE from the real ws_size and
// passed in: no unchecked OOB write is possible regardless of ws_size.

#define MAC(i, j, A, B) \
    acc[i][j] = fmaf(A.x, B.x, acc[i][j]); \
    acc[i][j] = fmaf(A.y, B.y, acc[i][j]); \
    acc[i][j] = fmaf(A.z, B.z, acc[i][j]); \
    acc[i][j] = fmaf(A.w, B.w, acc[i][j]);

// Round-0-homologous structure: single 32KB LDS buffer (well under the 64KB/WG
// edge both dirty rounds sat on), 2 barriers/step, NO registers carried across
// the compute phase (peak live ~80 VGPR -> no spill possible at the 128 cap).
// 33KB LDS -> 4 blocks/CU: inter-block TLP hides the stage latency.
__global__ __launch_bounds__(256, 4)
void moe_gate_main(const float* __restrict__ x,
                   const float* __restrict__ gw,
                   const float* __restrict__ bias,
                   float* __restrict__ out,
                   unsigned int* __restrict__ ws,
                   const unsigned int cap)
{
    __shared__ __align__(16) char smem[32768];     // W tile 16KB | X tile 16KB
    __shared__ unsigned int hist[NEXP];

    const int tid = threadIdx.x;
    const int t0  = blockIdx.x * TTILE;

    if (tid < NEXP) hist[tid] = 0;

    // staging geometry: thread (r0 = tid>>4, c = tid&15) covers rows r0+16s,
    // chunk c (16B). Global reads lane-linear (16 lanes = contiguous 256B row
    // slice). LDS write XOR-swizzled: chunk c of row r -> slot c^(r&7).
    // (r0+16s)&7 == r0&7, so the swizzled chunk is constant across s.
    const int r0  = tid >> 4;                      // 0..15
    const int c   = tid & 15;
    const float* xb0 = x  + (size_t)(t0 + r0) * DIM + 4 * c;
    const float* wb0 = gw + (size_t)r0        * DIM + 4 * c;
    const int ls0 = r0 * 256 + ((c ^ (r0 & 7)) << 4);   // byte offset in 16KB tile

    char* const Wt = smem;
    char* const Xt = smem + 16384;

    float acc[4][4];
    #pragma unroll
    for (int i = 0; i < 4; ++i)
        #pragma unroll
        for (int j = 0; j < 4; ++j) acc[i][j] = 0.0f;

    // compute-side mapping: experts eg+16i, tokens tg+16j; reads use the same
    // XOR swizzle -> conflict-free (verified bank math; proven in rounds 1-2)
    const int eg = tid & 15;
    const int tg = tid >> 4;
    const int wx = (eg & 7) << 4;
    const int tx = (tg & 7) << 4;

    for (int step = 0; step < NSTEP; ++step) {
        const int ko = step * BK;
        // issue loads BEFORE the buffer-free barrier: they fly under other
        // waves' compute of the previous step; drained at the ds_writes.
        const float4 xv0 = *(const float4*)(xb0 + ko);
        const float4 xv1 = *(const float4*)(xb0 + ko + 16 * DIM);
        const float4 xv2 = *(const float4*)(xb0 + ko + 32 * DIM);
        const float4 xv3 = *(const float4*)(xb0 + ko + 48 * DIM);
        const float4 wv0 = *(const float4*)(wb0 + ko);
        const float4 wv1 = *(const float4*)(wb0 + ko + 16 * DIM);
        const float4 wv2 = *(const float4*)(wb0 + ko + 32 * DIM);
        const float4 wv3 = *(const float4*)(wb0 + ko + 48 * DIM);
        __syncthreads();                           // prev step's reads done
        *(float4*)(Xt + ls0)         = xv0;
        *(float4*)(Xt + ls0 + 4096)  = xv1;
        *(float4*)(Xt + ls0 + 8192)  = xv2;
        *(float4*)(Xt + ls0 + 12288) = xv3;
        *(float4*)(Wt + ls0)         = wv0;
        *(float4*)(Wt + ls0 + 4096)  = wv1;
        *(float4*)(Wt + ls0 + 8192)  = wv2;
        *(float4*)(Wt + ls0 + 12288) = wv3;
        __syncthreads();                           // tile staged

        const char* wb = Wt + eg * 256;
        const char* xb = Xt + tg * 256;
        #pragma unroll
        for (int q = 0; q < 16; ++q) {
            const int wq = (q << 4) ^ wx;          // swizzled read slot
            const int xq = (q << 4) ^ tx;
            const float4 a0 = *(const float4*)(wb + wq);
            const float4 a1 = *(const float4*)(wb + 4096  + wq);
            const float4 a2 = *(const float4*)(wb + 8192  + wq);
            const float4 a3 = *(const float4*)(wb + 12288 + wq);
            const float4 b0 = *(const float4*)(xb + xq);
            const float4 b1 = *(const float4*)(xb + 4096  + xq);
            const float4 b2 = *(const float4*)(xb + 8192  + xq);
            const float4 b3 = *(const float4*)(xb + 12288 + xq);
            MAC(0,0,a0,b0) MAC(0,1,a0,b1) MAC(0,2,a0,b2) MAC(0,3,a0,b3)
            MAC(1,0,a1,b0) MAC(1,1,a1,b1) MAC(1,2,a1,b2) MAC(1,3,a1,b3)
            MAC(2,0,a2,b0) MAC(2,1,a2,b1) MAC(2,2,a2,b2) MAC(2,3,a2,b3)
            MAC(3,0,a3,b0) MAC(3,1,a3,b1) MAC(3,2,a3,b2) MAC(3,3,a3,b3)
        }
    }

    // ---- dump scores (+bias) to LDS: S[e][t], stride 65 floats (16.6KB) ----
    __syncthreads();
    float* S = (float*)smem;
    #pragma unroll
    for (int i = 0; i < 4; ++i) {
        const int e = eg + 16 * i;
        const float b = bias[e];
        #pragma unroll
        for (int j = 0; j < 4; ++j)
            S[e * 65 + tg + 16 * j] = acc[i][j] + b;
    }
    __syncthreads();

    if (tid < TTILE) {
        const int t = tid;
        // top-9 (descending, lowest index first on ties — strict '>')
        float bv[9]; int bi[9];
        #pragma unroll
        for (int j = 0; j < 9; ++j) { bv[j] = -INFINITY; bi[j] = 0; }
        for (int e = 0; e < NEXP; ++e) {
            const float v = S[e * 65 + t];
            if (v > bv[8]) {
                bv[8] = v; bi[8] = e;
                #pragma unroll
                for (int j = 8; j > 0; --j) {
                    if (bv[j] > bv[j - 1]) {
                        const float tv = bv[j]; bv[j] = bv[j-1]; bv[j-1] = tv;
                        const int   ti = bi[j]; bi[j] = bi[j-1]; bi[j-1] = ti;
                    }
                }
            }
        }
        // ambiguity: any adjacent gap in sorted top-9 below guard -> f64 refine
        float ming = bv[0] - bv[1];
        #pragma unroll
        for (int j = 1; j < 8; ++j) ming = fminf(ming, bv[j] - bv[j + 1]);
        bool amb = (ming < GAP_TH);

        if (amb) {
            const unsigned slot = atomicAdd(ws + NEXP, 1u);
            if (slot < cap) ws[NEXP + 1 + slot] = (unsigned)(t0 + t);
            else            amb = false;           // list full: fall back to f32 result
        }

        const float m = bv[0];
        float Z = 0.0f;
        for (int e = 0; e < NEXP; ++e) Z += expf(S[e * 65 + t] - m);
        const float rZ = 1.0f / Z;
        float p[TOPK]; float wsum = 0.0f;
        #pragma unroll
        for (int j = 0; j < TOPK; ++j) { p[j] = expf(bv[j] - m) * rZ; wsum += p[j]; }
        const float rd = 1.0f / (wsum + 1e-8f);

        const size_t tglob = (size_t)(t0 + t);
        float4 w0 = { p[0]*rd, p[1]*rd, p[2]*rd, p[3]*rd };
        float4 w1 = { p[4]*rd, p[5]*rd, p[6]*rd, p[7]*rd };
        *(float4*)(out + OFF_W + tglob * TOPK)     = w0;
        *(float4*)(out + OFF_W + tglob * TOPK + 4) = w1;
        float4 i0 = { (float)bi[0], (float)bi[1], (float)bi[2], (float)bi[3] };
        float4 i1 = { (float)bi[4], (float)bi[5], (float)bi[6], (float)bi[7] };
        *(float4*)(out + OFF_IDX + tglob * TOPK)     = i0;
        *(float4*)(out + OFF_IDX + tglob * TOPK + 4) = i1;

        if (!amb) {
            #pragma unroll
            for (int j = 0; j < TOPK; ++j) atomicAdd(&hist[bi[j]], 1u);
        }
    }

    __syncthreads();
    if (tid < NEXP) atomicAdd(ws + tid, hist[tid]);
}

// f64 re-resolve of flagged tokens: identical math/rounding/tie semantics as the
// previously-passing f64 kernel ((float)acc + bias, strict-> insertion, expf softmax).
__global__ __launch_bounds__(256)
void moe_gate_refine(const float* __restrict__ x,
                     const float* __restrict__ gw,
                     const float* __restrict__ bias,
                     float* __restrict__ out,
                     unsigned int* __restrict__ ws,
                     const unsigned int cap)
{
    __shared__ __align__(16) float xs[DIM];
    __shared__ float S[NEXP];
    const unsigned nf = ws[NEXP];
    const unsigned nflag = nf < cap ? nf : cap;
    const unsigned* list = ws + NEXP + 1;

    for (unsigned ii = blockIdx.x; ii < nflag; ii += gridDim.x) {
        const size_t t = (size_t)list[ii];
        __syncthreads();                         // protect xs/S reuse across iters
        #pragma unroll
        for (int jj = 0; jj < 2; ++jj) {
            const int f = threadIdx.x + jj * 256;     // float4 index 0..511
            ((float4*)xs)[f] = ((const float4*)(x + t * DIM))[f];
        }
        __syncthreads();

        const int e = threadIdx.x >> 2;          // 4 threads per expert
        const int q = threadIdx.x & 3;
        const float* wr = gw + (size_t)e * DIM + q * 512;
        const float* xr = xs + q * 512;
        double s = 0.0;
        for (int k = 0; k < 512; k += 4) {
            const float4 wv4 = *(const float4*)(wr + k);
            const float4 xv4 = *(const float4*)(xr + k);
            s = fma((double)wv4.x, (double)xv4.x, s);
            s = fma((double)wv4.y, (double)xv4.y, s);
            s = fma((double)wv4.z, (double)xv4.z, s);
            s = fma((double)wv4.w, (double)xv4.w, s);
        }
        s += __shfl_down(s, 2, 4);
        s += __shfl_down(s, 1, 4);
        if (q == 0) S[e] = (float)s + bias[e];
        __syncthreads();

        if (threadIdx.x == 0) {
            float bv[TOPK]; int bi[TOPK];
            #pragma unroll
            for (int j = 0; j < TOPK; ++j) { bv[j] = -INFINITY; bi[j] = 0; }
            for (int e2 = 0; e2 < NEXP; ++e2) {
                const float v = S[e2];
                if (v > bv[TOPK - 1]) {
                    bv[TOPK - 1] = v; bi[TOPK - 1] = e2;
                    #pragma unroll
                    for (int j = TOPK - 1; j > 0; --j) {
                        if (bv[j] > bv[j - 1]) {
                            const float tv = bv[j]; bv[j] = bv[j-1]; bv[j-1] = tv;
                            const int   ti = bi[j]; bi[j] = bi[j-1]; bi[j-1] = ti;
                        }
                    }
                }
            }
            const float m = bv[0];
            float Z = 0.0f;
            for (int e2 = 0; e2 < NEXP; ++e2) Z += expf(S[e2] - m);
            const float rZ = 1.0f / Z;
            float p[TOPK]; float wsum = 0.0f;
            #pragma unroll
            for (int j = 0; j < TOPK; ++j) { p[j] = expf(bv[j] - m) * rZ; wsum += p[j]; }
            const float rd = 1.0f / (wsum + 1e-8f);

            float4 w0 = { p[0]*rd, p[1]*rd, p[2]*rd, p[3]*rd };
            float4 w1 = { p[4]*rd, p[5]*rd, p[6]*rd, p[7]*rd };
            *(float4*)(out + OFF_W + t * TOPK)     = w0;
            *(float4*)(out + OFF_W + t * TOPK + 4) = w1;
            float4 i0 = { (float)bi[0], (float)bi[1], (float)bi[2], (float)bi[3] };
            float4 i1 = { (float)bi[4], (float)bi[5], (float)bi[6], (float)bi[7] };
            *(float4*)(out + OFF_IDX + t * TOPK)     = i0;
            *(float4*)(out + OFF_IDX + t * TOPK + 4) = i1;

            #pragma unroll
            for (int j = 0; j < TOPK; ++j) atomicAdd(ws + bi[j], 1u);
        }
    }
}

__global__ void moe_gate_fin(const unsigned int* __restrict__ cnt,
                             const float* __restrict__ bias,
                             const float* __restrict__ eu,
                             float* __restrict__ out)
{
    const int e = threadIdx.x;
    const float usage = (float)cnt[e] * (1.0f / (float)(T_TOT * TOPK));
    out[OFF_B + e] = bias[e] - 0.01f * (usage - 1.0f / (float)NEXP);
    out[OFF_U + e] = 0.9f * eu[e] + 0.1f * usage;
}

extern "C" void kernel_launch(void* const* d_in, const int* in_sizes, int n_in,
                              void* d_out, int out_size, void* d_ws, size_t ws_size,
                              hipStream_t stream) {
    const float* x    = (const float*)d_in[0];
    const float* gw   = (const float*)d_in[1];
    const float* bias = (const float*)d_in[2];
    const float* eu   = (const float*)d_in[3];
    float* out = (float*)d_out;
    unsigned int* cnt = (unsigned int*)d_ws;

    // flag-list capacity from the REAL workspace size (no unchecked OOB possible)
    const size_t ws_words = ws_size / sizeof(unsigned int);
    const unsigned cap = ws_words > (size_t)(NEXP + 1)
                       ? (unsigned)(ws_words - (NEXP + 1)) : 0u;

    hipMemsetAsync(cnt, 0, (NEXP + 1) * sizeof(unsigned int), stream);
    moe_gate_main<<<T_TOT / TTILE, 256, 0, stream>>>(x, gw, bias, out, cnt, cap);
    moe_gate_refine<<<256, 256, 0, stream>>>(x, gw, bias, out, cnt, cap);
    moe_gate_fin<<<1, NEXP, 0, stream>>>(cnt, bias, eu, out);
}